// Round 12
// baseline (190.332 us; speedup 1.0000x reference)
//
#include <hip/hip_runtime.h>

// PolylineEncoder: h = relu(X@W1+b1); feat = h@W2+b2; masked max over N=64 points.
// B=32 P=512 N=64 C=9 H=128.  Block = 2 polylines (128 points), grid 8192.
// R12 = R8 (32x32x16 layer-2, mask folded into GEMM as K-column, in-reg pool
// tree) with the layer-2 loop INVERTED: ks-outer / dt-inner -> 4 independent
// MFMA chains (R8's dt-outer made 4 serial 9-deep chains, each MFMA gated on a
// just-issued load => 126us despite the lowest VALU count of any round).
// Layer1 stays on verified 16x16x32.  LDS 37376 B -> 4 blocks/CU.
// NOT the shfl-butterfly epilogue (R2/R10/R11: ds_bpermute chains lose to the
// LDS-transpose path every time).

using bf16x8 = __attribute__((ext_vector_type(8))) short;
using f32x4  = __attribute__((ext_vector_type(4))) float;
using f32x16 = __attribute__((ext_vector_type(16))) float;

#define MFMA16x16(A,B,C) __builtin_amdgcn_mfma_f32_16x16x32_bf16((A),(B),(C),0,0,0)
#define MFMA32x32(A,B,C) __builtin_amdgcn_mfma_f32_32x32x16_bf16((A),(B),(C),0,0,0)

__device__ __forceinline__ f32x4 vmax4(f32x4 a, f32x4 b) {
  return __builtin_elementwise_max(a, b);
}

__device__ __forceinline__ unsigned short f2bf(float f) {
  union { float f; unsigned int u; } v; v.f = f;
  unsigned int r = v.u + 0x7fffu + ((v.u >> 16) & 1u);  // RNE
  return (unsigned short)(r >> 16);
}

// pack two floats to bf16x2 (round-half-up) via v_perm
__device__ __forceinline__ unsigned int pack_bf2(float a, float b) {
  union { float f; unsigned int u; } ua, ub; ua.f = a; ub.f = b;
  return __builtin_amdgcn_perm(ub.u + 0x8000u, ua.u + 0x8000u, 0x07060302u);
}

// ---------------- prep1: mask sniff + frag-swizzled weights ----------------
// ws: w1sw @0 (8192B) | w2sw @8192 (36864B) | flag @45056
__global__ void prep1(const float* __restrict__ W1, const float* __restrict__ W2,
                      const void* __restrict__ mask,
                      unsigned short* __restrict__ w1sw, unsigned short* __restrict__ w2sw,
                      int* __restrict__ flag) {
  int b = blockIdx.x, t = threadIdx.x;
  if (b == 0) {                      // mask storage sniff over 4096 bytes
    __shared__ int cnt;
    if (t == 0) cnt = 0;
    __syncthreads();
    const unsigned char* mb = (const unsigned char*)mask;
    int local = 0;
    for (int i = t * 16; i < t * 16 + 16; i++) local += (mb[i] != 0) ? 1 : 0;
    atomicAdd(&cnt, local);
    __syncthreads();
    if (t == 0) *flag = (cnt > 2800) ? 1 : 0;   // 1 = byte-wise mask, else int32-wise
  } else if (b <= 2) {
    // w1 A-frags (16x16x32): entry e = (wr*4+th)*64 + lane; h=(e>>6)*16+(lane&15)
    int e = (b - 1) * 256 + t;       // 512 entries x 8 halves = 8KB
    int lane = e & 63, grp = e >> 6;
    int li = lane & 15, q = lane >> 4;
    int h = grp * 16 + li;
    int c0 = q * 8;
    #pragma unroll
    for (int j = 0; j < 8; j++) {
      int c = c0 + j;
      w1sw[e * 8 + j] = f2bf((c < 9) ? W1[c * 128 + h] : 0.f);
    }
  } else {
    // w2 B-frags (32x32x16): entry e = (dt*9+kb)*64 + lane; 8 halves each
    // B[k][d]: d = dt*32 + (lane&31), k = kb*16 + (lane>>5)*8 + j
    // k==128 carries the mask penalty row (-4e9); k>128 zero.
    int e = (b - 3) * 256 + t;       // 2304 entries x 8 halves = 36864B
    if (e < 2304) {
      int lane = e & 63, grp = e >> 6;       // grp = dt*9 + kb, 0..35
      int dt = grp / 9, kb = grp - dt * 9;
      int d = dt * 32 + (lane & 31);
      int k0 = kb * 16 + (lane >> 5) * 8;
      #pragma unroll
      for (int j = 0; j < 8; j++) {
        int k = k0 + j;
        float v = (k < 128) ? W2[k * 128 + d] : ((k == 128) ? -4e9f : 0.f);
        w2sw[e * 8 + j] = f2bf(v);
      }
    }
  }
}

// ---------------- main ----------------
// LDS arena 37376 B:
//   [0, 4608)  Xs  raw f32 X block            (b0 .. bfb)
//   whole      Hs  H rows [m][k], stride 146 u16, k:0..127 feat, 128 mask col,
//              129..143 zero                  (bfb .. b2)
//   [0, 2048)  P   per-wave pooled partials   (b2 .. end)
__global__ __launch_bounds__(256, 4) void poly_main_k(
    const float* __restrict__ X, const void* __restrict__ mask,
    const float* __restrict__ b1g, const float* __restrict__ b2g,
    const unsigned short* __restrict__ w1sw, const unsigned short* __restrict__ w2sw,
    const int* __restrict__ flagp, float* __restrict__ out)
{
  __shared__ __align__(16) unsigned char smem[128 * 146 * 2];
  float*          Xs = (float*)smem;
  unsigned short* Hs = (unsigned short*)smem;
  float*          P  = (float*)smem;

  const int tid  = threadIdx.x;
  const int lane = tid & 63;
  const int w    = tid >> 6;
  const int wr   = w >> 1, wc = w & 1;   // layer-1 wave grid: wr = h half, wc = polyline
  const int li   = lane & 15, q = lane >> 4;

  // ---- stage X: 288 float4 coalesced global -> LDS b128 ----
  {
    const f32x4* xg = (const f32x4*)(X + (long long)blockIdx.x * 1152);
    f32x4* xl = (f32x4*)Xs;
    xl[tid] = xg[tid];
    if (tid < 32) xl[tid + 256] = xg[tid + 256];
  }
  __syncthreads();  // b0: Xs ready

  // ---- layer-1 B-frags from Xs: B[m][k], k=q*8+j, only c<9 nonzero ----
  bf16x8 bx[4];
  #pragma unroll
  for (int tm = 0; tm < 4; tm++) {
    int m = wc * 64 + tm * 16 + li;
    const float* xr = Xs + m * 9;
    union { bf16x8 v; unsigned int u[4]; } uu;
    uu.u[0] = uu.u[1] = uu.u[2] = uu.u[3] = 0u;
    if (q == 0) {
      uu.u[0] = pack_bf2(xr[0], xr[1]); uu.u[1] = pack_bf2(xr[2], xr[3]);
      uu.u[2] = pack_bf2(xr[4], xr[5]); uu.u[3] = pack_bf2(xr[6], xr[7]);
    } else if (q == 1) {
      uu.u[0] = pack_bf2(xr[8], 0.f);
    }
    bx[tm] = uu.v;
  }
  __syncthreads();  // bfb: all Xs reads done -> Hs may overwrite arena

  // ---- layer 1 (verified 16x16x32), th-outer, bias in MFMA C-init ----
  #pragma unroll
  for (int th = 0; th < 4; th++) {
    bf16x8 a1 = *(const bf16x8*)(w1sw + ((wr * 4 + th) * 64 + lane) * 8);
    f32x4 bv = *(const f32x4*)(b1g + wr * 64 + th * 16 + q * 4);
    f32x4 acc[4];
    #pragma unroll
    for (int tm = 0; tm < 4; tm++) acc[tm] = bv;
    #pragma unroll
    for (int tm = 0; tm < 4; tm++) acc[tm] = MFMA16x16(a1, bx[tm], acc[tm]);
    // epilogue: relu, pack, write H[m][h] (4 consecutive h per lane -> b64)
    #pragma unroll
    for (int tm = 0; tm < 4; tm++) {
      int m = wc * 64 + tm * 16 + li;
      f32x4 v = vmax4(acc[tm], f32x4{0.f, 0.f, 0.f, 0.f});
      uint2 hv;
      hv.x = pack_bf2(v[0], v[1]);
      hv.y = pack_bf2(v[2], v[3]);
      *(uint2*)(Hs + m * 146 + wr * 64 + th * 16 + q * 4) = hv;
    }
  }

  // ---- mask indicator column: H[m][128] = invalid ? 1 : 0; 129..143 = 0 ----
  {
    int flag = *flagp;
    int m2 = tid >> 1, half = tid & 1;
    long long gi = (long long)blockIdx.x * 128 + m2;
    unsigned int ind = 0u;
    if (half == 0) {
      bool valid = flag ? (((const unsigned char*)mask)[gi] != 0)
                        : (((const int*)mask)[gi] != 0);
      ind = valid ? 0u : 0x00003F80u;   // bf16(1.0) in low u16 (k=128)
    }
    unsigned int* dst = (unsigned int*)(Hs + m2 * 146 + 128) + half * 4;
    dst[0] = ind; dst[1] = 0u; dst[2] = 0u; dst[3] = 0u;
  }
  __syncthreads();  // b1: Hs ready (feat + mask col)

  // ---- layer 2: 32x32x16, D[m][d] = H(A) x W2(B), K=144, ks-outer dt-inner ----
  // A: row m = w*32 + (lane&31), k = kb*16 + (lane>>5)*8 + j  (ds_read_b128)
  // C/D (verified): col d = lane&31 (+dt*32), row m = (reg&3)+8*(reg>>2)+4*(lane>>5)
  float pool[4];
  {
    const unsigned short* abase = Hs + (w * 32 + (lane & 31)) * 146 + (lane >> 5) * 8;
    f32x16 acc[4];
    #pragma unroll
    for (int dt = 0; dt < 4; dt++) acc[dt] = f32x16{0.f};
    #pragma unroll
    for (int kb = 0; kb < 9; kb++) {
      bf16x8 af = *(const bf16x8*)(abase + kb * 16);
      bf16x8 bf0 = *(const bf16x8*)(w2sw + ((0 * 9 + kb) * 64 + lane) * 8);
      bf16x8 bf1 = *(const bf16x8*)(w2sw + ((1 * 9 + kb) * 64 + lane) * 8);
      bf16x8 bf2 = *(const bf16x8*)(w2sw + ((2 * 9 + kb) * 64 + lane) * 8);
      bf16x8 bf3 = *(const bf16x8*)(w2sw + ((3 * 9 + kb) * 64 + lane) * 8);
      acc[0] = MFMA32x32(af, bf0, acc[0]);   // 4 independent chains
      acc[1] = MFMA32x32(af, bf1, acc[1]);
      acc[2] = MFMA32x32(af, bf2, acc[2]);
      acc[3] = MFMA32x32(af, bf3, acc[3]);
    }
    // pool over the 16 m-rows held in-lane (mask applied via k=128 column)
    #pragma unroll
    for (int dt = 0; dt < 4; dt++) {
      f32x16 a = acc[dt];
      float p0 = fmaxf(fmaxf(a[0],  a[1]),  fmaxf(a[2],  a[3]));
      float p1 = fmaxf(fmaxf(a[4],  a[5]),  fmaxf(a[6],  a[7]));
      float p2 = fmaxf(fmaxf(a[8],  a[9]),  fmaxf(a[10], a[11]));
      float p3 = fmaxf(fmaxf(a[12], a[13]), fmaxf(a[14], a[15]));
      float pm = fmaxf(fmaxf(p0, p1), fmaxf(p2, p3));
      pm = fmaxf(pm, __shfl_xor(pm, 32, 64));   // combine the two m-halves
      pool[dt] = pm + b2g[dt * 32 + (lane & 31)];
    }
  }

  __syncthreads();  // b2: all Hs reads done -> reuse arena as P
  // wave w pooled over its 32 m-rows; waves {0,1}=poly0, {2,3}=poly1
  if (lane < 32) {
    #pragma unroll
    for (int dt = 0; dt < 4; dt++)
      P[w * 128 + dt * 32 + lane] = pool[dt];
  }
  __syncthreads();  // b3: P ready

  // ---- final: combine wave pairs, all-invalid -> 0, coalesced store ----
  {
    int p = tid >> 7, d = tid & 127;
    float v = fmaxf(P[(2 * p) * 128 + d], P[(2 * p + 1) * 128 + d]);
    if (v < -1e8f) v = 0.f;
    out[(long long)blockIdx.x * 256 + tid] = v;
  }
}

extern "C" void kernel_launch(void* const* d_in, const int* in_sizes, int n_in,
                              void* d_out, int out_size, void* d_ws, size_t ws_size,
                              hipStream_t stream) {
  const float* X    = (const float*)d_in[0];
  const void*  mask = d_in[1];
  const float* W1   = (const float*)d_in[2];
  const float* b1   = (const float*)d_in[3];
  const float* W2   = (const float*)d_in[4];
  const float* b2   = (const float*)d_in[5];
  float* out = (float*)d_out;

  unsigned short* w1sw = (unsigned short*)d_ws;
  unsigned short* w2sw = (unsigned short*)((char*)d_ws + 8192);
  int* flag            = (int*)((char*)d_ws + 45056);

  prep1<<<12, 256, 0, stream>>>(W1, W2, mask, w1sw, w2sw, flag);
  poly_main_k<<<8192, 256, 0, stream>>>(X, mask, b1, b2, w1sw, w2sw, flag, out);
}